// Round 1
// baseline (5006.088 us; speedup 1.0000x reference)
//
#include <hip/hip_runtime.h>
#include <math.h>

// BERTStudentPruner on MI355X.
// Pipeline:
//   H1 = relu(X @ W1^T + b1)                      [131072, 768]  -> d_ws
//   logit = (relu(H1 @ W2^T + b2)) @ w3  (fused)  [131072]       -> d_out[0:M] (scratch)
//   y_soft = sigmoid(logit + b3)                  [131072]       -> d_out[M:2M]
//   y_hard = stable-rank(y_soft row-wise) < k     [131072]       -> d_out[0:M]
// Rank semantics: token 0 forced below global min => rank 0 (always kept) and
// contributes +1 to every other element's rank; stable ties broken by index.

#define BM 64
#define BN 64
#define BK 16

// ---------------------------------------------------------------- GEMM 1
// C[m,n] = relu(sum_k A[m,k]*B[n,k] + bias[n]);  A:[M,K] B:[N,K] row-major.
__global__ __launch_bounds__(256) void gemm_relu_kernel(
    const float* __restrict__ A, const float* __restrict__ B,
    const float* __restrict__ bias, float* __restrict__ C,
    int M, int N, int K)
{
  __shared__ float As[BK][BM + 4];
  __shared__ float Bs[BK][BN + 4];
  const int bn = blockIdx.x * BN;     // grid.x = N/BN (fastest) -> A-row reuse in L2
  const int bm = blockIdx.y * BM;
  const int tid = threadIdx.x;
  const int tx = tid & 15, ty = tid >> 4;
  const int lrow = tid >> 2;          // 0..63
  const int lk = (tid & 3) << 2;      // 0,4,8,12

  float acc[4][4] = {};
  const float* Aptr = A + (size_t)(bm + lrow) * K + lk;
  const float* Bptr = B + (size_t)(bn + lrow) * K + lk;

  for (int k0 = 0; k0 < K; k0 += BK) {
    float4 av = *(const float4*)(Aptr + k0);
    float4 bv = *(const float4*)(Bptr + k0);
    __syncthreads();
    As[lk + 0][lrow] = av.x;
    As[lk + 1][lrow] = av.y;
    As[lk + 2][lrow] = av.z;
    As[lk + 3][lrow] = av.w;
    Bs[lk + 0][lrow] = bv.x;
    Bs[lk + 1][lrow] = bv.y;
    Bs[lk + 2][lrow] = bv.z;
    Bs[lk + 3][lrow] = bv.w;
    __syncthreads();
#pragma unroll
    for (int kk = 0; kk < BK; ++kk) {
      float4 a4 = *(const float4*)&As[kk][ty << 2];
      float4 b4 = *(const float4*)&Bs[kk][tx << 2];
      float ar[4] = {a4.x, a4.y, a4.z, a4.w};
      float br[4] = {b4.x, b4.y, b4.z, b4.w};
#pragma unroll
      for (int i = 0; i < 4; ++i)
#pragma unroll
        for (int j = 0; j < 4; ++j)
          acc[i][j] = fmaf(ar[i], br[j], acc[i][j]);
    }
  }

#pragma unroll
  for (int i = 0; i < 4; ++i) {
    float* crow = C + (size_t)(bm + (ty << 2) + i) * N + bn + (tx << 2);
#pragma unroll
    for (int j = 0; j < 4; ++j) {
      float v = acc[i][j] + bias[bn + (tx << 2) + j];
      crow[j] = v > 0.f ? v : 0.f;
    }
  }
}

// ------------------------------------------------- GEMM 2 + fused w3 dot
// part[m] += sum_n relu(acc[m,n]+b2[n]) * w3[n]; atomicAdd into ylogit[m].
__global__ __launch_bounds__(256) void gemm_score_kernel(
    const float* __restrict__ A, const float* __restrict__ B,
    const float* __restrict__ bias, const float* __restrict__ w3,
    float* __restrict__ ylogit, int M, int N, int K)
{
  __shared__ float As[BK][BM + 4];
  __shared__ float Bs[BK][BN + 4];
  const int bn = blockIdx.x * BN;
  const int bm = blockIdx.y * BM;
  const int tid = threadIdx.x;
  const int tx = tid & 15, ty = tid >> 4;
  const int lrow = tid >> 2;
  const int lk = (tid & 3) << 2;

  float acc[4][4] = {};
  const float* Aptr = A + (size_t)(bm + lrow) * K + lk;
  const float* Bptr = B + (size_t)(bn + lrow) * K + lk;

  for (int k0 = 0; k0 < K; k0 += BK) {
    float4 av = *(const float4*)(Aptr + k0);
    float4 bv = *(const float4*)(Bptr + k0);
    __syncthreads();
    As[lk + 0][lrow] = av.x;
    As[lk + 1][lrow] = av.y;
    As[lk + 2][lrow] = av.z;
    As[lk + 3][lrow] = av.w;
    Bs[lk + 0][lrow] = bv.x;
    Bs[lk + 1][lrow] = bv.y;
    Bs[lk + 2][lrow] = bv.z;
    Bs[lk + 3][lrow] = bv.w;
    __syncthreads();
#pragma unroll
    for (int kk = 0; kk < BK; ++kk) {
      float4 a4 = *(const float4*)&As[kk][ty << 2];
      float4 b4 = *(const float4*)&Bs[kk][tx << 2];
      float ar[4] = {a4.x, a4.y, a4.z, a4.w};
      float br[4] = {b4.x, b4.y, b4.z, b4.w};
#pragma unroll
      for (int i = 0; i < 4; ++i)
#pragma unroll
        for (int j = 0; j < 4; ++j)
          acc[i][j] = fmaf(ar[i], br[j], acc[i][j]);
    }
  }

  // Epilogue: relu + partial dot with w3 over this tile's 64 columns.
  float part[4];
#pragma unroll
  for (int i = 0; i < 4; ++i) {
    float p = 0.f;
#pragma unroll
    for (int j = 0; j < 4; ++j) {
      int n = bn + (tx << 2) + j;
      float v = acc[i][j] + bias[n];
      v = v > 0.f ? v : 0.f;
      p = fmaf(v, w3[n], p);
    }
    part[i] = p;
  }
  // Reduce across the 16 tx-lanes (contiguous lanes within one wave).
#pragma unroll
  for (int off = 1; off < 16; off <<= 1) {
#pragma unroll
    for (int i = 0; i < 4; ++i)
      part[i] += __shfl_xor(part[i], off, 64);
  }
  if (tx == 0) {
#pragma unroll
    for (int i = 0; i < 4; ++i)
      atomicAdd(&ylogit[bm + (ty << 2) + i], part[i]);
  }
}

// ---------------------------------------------------------------- sigmoid
__global__ void sigmoid_kernel(const float* __restrict__ logit,
                               const float* __restrict__ b3,
                               float* __restrict__ ysoft, int n)
{
  int i = blockIdx.x * blockDim.x + threadIdx.x;
  if (i < n) {
    float x = logit[i] + b3[0];
    ysoft[i] = 1.f / (1.f + expf(-x));
  }
}

// ------------------------------------------------------------------ rank
// One block per batch row. rank[j] = #{y[i]<y[j]} + #{i<j: y[i]==y[j]},
// with token 0 treated as -inf (always rank 0, +1 to everyone else).
__global__ __launch_bounds__(256) void rank_kernel(
    const float* __restrict__ ysoft, float* __restrict__ yhard,
    const int* __restrict__ kptr, int S)
{
  __shared__ float row[2048];
  const int b = blockIdx.x;
  const float* y = ysoft + (size_t)b * S;
  float* out = yhard + (size_t)b * S;
  const int kk = *kptr;

  for (int i = threadIdx.x; i < S; i += 256) row[i] = y[i];
  __syncthreads();

  for (int j = threadIdx.x; j < S; j += 256) {
    if (j == 0) { out[0] = 1.0f; continue; }
    const float v = row[j];
    int cnt = 1;  // token 0 is always strictly smaller
    for (int i = 1; i < S; ++i) {
      float u = row[i];
      if (u < v || (u == v && i < j)) ++cnt;
    }
    out[j] = (cnt < kk) ? 1.0f : 0.0f;
  }
}

// ------------------------------------------------------------------ launch
extern "C" void kernel_launch(void* const* d_in, const int* in_sizes, int n_in,
                              void* d_out, int out_size, void* d_ws, size_t ws_size,
                              hipStream_t stream)
{
  const float* X  = (const float*)d_in[0];
  const float* W1 = (const float*)d_in[1];
  const float* b1 = (const float*)d_in[2];
  const float* W2 = (const float*)d_in[3];
  const float* b2 = (const float*)d_in[4];
  const float* W3 = (const float*)d_in[5];
  const float* b3 = (const float*)d_in[6];
  const int*  kpt = (const int*)d_in[7];

  const int D = 768;
  const int M = in_sizes[0] / D;   // B*S = 131072
  const int S = 2048;
  const int Bb = M / S;            // 64

  float* H1     = (float*)d_ws;            // M*D floats (~402 MB)
  float* ylogit = (float*)d_out;           // first M floats, scratch
  float* yhard  = (float*)d_out;
  float* ysoft  = ((float*)d_out) + M;

  hipMemsetAsync(ylogit, 0, (size_t)M * sizeof(float), stream);

  dim3 blk(256);
  dim3 g(D / BN, M / BM);  // (12, 2048): N-tiles fastest for A-row L2 reuse
  gemm_relu_kernel<<<g, blk, 0, stream>>>(X, W1, b1, H1, M, D, D);
  gemm_score_kernel<<<g, blk, 0, stream>>>(H1, W2, b2, W3, ylogit, M, D, D);
  sigmoid_kernel<<<dim3((M + 255) / 256), blk, 0, stream>>>(ylogit, b3, ysoft, M);
  rank_kernel<<<dim3(Bb), blk, 0, stream>>>(ysoft, yhard, kpt, S);
}

// Round 2
// 4358.000 us; speedup vs baseline: 1.1487x; 1.1487x over previous
//
#include <hip/hip_runtime.h>
#include <math.h>

// BERTStudentPruner on MI355X.
//   H1 = relu(X @ W1^T + b1)                      [131072, 768]  -> d_ws
//   logit = (relu(H1 @ W2^T + b2)) @ w3  (fused)  [131072]       -> d_out[0:M] (scratch)
//   y_soft = sigmoid(logit + b3)                  [131072]       -> d_out[M:2M]
//   y_hard = stable-rank(y_soft row-wise) < k     [131072]       -> d_out[0:M]
// Rank semantics: token 0 forced below global min => rank 0 (always kept) and
// contributes +1 to every other element's rank; stable ties broken by index.
// Precision note: min rank-cut gap across 64 rows ~7e-7 in score space, so the
// GEMMs stay fp32 (no fp32 MFMA on CDNA4 -> vector ALU, 157 TF ceiling).

#define BM 128
#define BN 128
#define BK 16
// 256 threads, 8x8 register tile each: rows {ty*4+i, 64+ty*4+i},
// cols {tx*4+j, 64+tx*4+j}.

// ---------------------------------------------------------------- GEMM 1
// C[m,n] = relu(sum_k A[m,k]*B[n,k] + bias[n]);  A:[M,K] B:[N,K] row-major.
__global__ __launch_bounds__(256) void gemm_relu_kernel(
    const float* __restrict__ A, const float* __restrict__ B,
    const float* __restrict__ bias, float* __restrict__ C,
    int M, int N, int K)
{
  __shared__ float As[BK][BM + 4];
  __shared__ float Bs[BK][BN + 4];
  const int bn = blockIdx.x * BN;     // grid.x = N/BN (fastest) -> A-row reuse in L2
  const int bm = blockIdx.y * BM;
  const int tid = threadIdx.x;
  const int tx = tid & 15, ty = (tid >> 4);
  const int lrow = tid >> 1;          // 0..127 staging row
  const int lk = (tid & 1) * 8;       // k-chunk 0 or 8

  float acc[8][8] = {};
  const float* Aptr = A + (size_t)(bm + lrow) * K + lk;
  const float* Bptr = B + (size_t)(bn + lrow) * K + lk;

  for (int k0 = 0; k0 < K; k0 += BK) {
    float4 av0 = *(const float4*)(Aptr + k0);
    float4 av1 = *(const float4*)(Aptr + k0 + 4);
    float4 bv0 = *(const float4*)(Bptr + k0);
    float4 bv1 = *(const float4*)(Bptr + k0 + 4);
    __syncthreads();
    As[lk + 0][lrow] = av0.x; As[lk + 1][lrow] = av0.y;
    As[lk + 2][lrow] = av0.z; As[lk + 3][lrow] = av0.w;
    As[lk + 4][lrow] = av1.x; As[lk + 5][lrow] = av1.y;
    As[lk + 6][lrow] = av1.z; As[lk + 7][lrow] = av1.w;
    Bs[lk + 0][lrow] = bv0.x; Bs[lk + 1][lrow] = bv0.y;
    Bs[lk + 2][lrow] = bv0.z; Bs[lk + 3][lrow] = bv0.w;
    Bs[lk + 4][lrow] = bv1.x; Bs[lk + 5][lrow] = bv1.y;
    Bs[lk + 6][lrow] = bv1.z; Bs[lk + 7][lrow] = bv1.w;
    __syncthreads();
#pragma unroll
    for (int kk = 0; kk < BK; ++kk) {
      float4 a0 = *(const float4*)&As[kk][ty << 2];
      float4 a1 = *(const float4*)&As[kk][64 + (ty << 2)];
      float4 b0 = *(const float4*)&Bs[kk][tx << 2];
      float4 b1 = *(const float4*)&Bs[kk][64 + (tx << 2)];
      float ar[8] = {a0.x, a0.y, a0.z, a0.w, a1.x, a1.y, a1.z, a1.w};
      float br[8] = {b0.x, b0.y, b0.z, b0.w, b1.x, b1.y, b1.z, b1.w};
#pragma unroll
      for (int i = 0; i < 8; ++i)
#pragma unroll
        for (int j = 0; j < 8; ++j)
          acc[i][j] = fmaf(ar[i], br[j], acc[i][j]);
    }
  }

  const float4 bias0 = *(const float4*)&bias[bn + (tx << 2)];
  const float4 bias1 = *(const float4*)&bias[bn + 64 + (tx << 2)];
  const float bb0[4] = {bias0.x, bias0.y, bias0.z, bias0.w};
  const float bb1[4] = {bias1.x, bias1.y, bias1.z, bias1.w};
#pragma unroll
  for (int i = 0; i < 8; ++i) {
    const int row = bm + ((i < 4) ? (ty << 2) + i : 64 + (ty << 2) + (i - 4));
    float4 o0, o1;
    float* o0p = (float*)&o0; float* o1p = (float*)&o1;
#pragma unroll
    for (int j = 0; j < 4; ++j) {
      float v0 = acc[i][j] + bb0[j];
      float v1 = acc[i][4 + j] + bb1[j];
      o0p[j] = v0 > 0.f ? v0 : 0.f;
      o1p[j] = v1 > 0.f ? v1 : 0.f;
    }
    *(float4*)(C + (size_t)row * N + bn + (tx << 2)) = o0;
    *(float4*)(C + (size_t)row * N + bn + 64 + (tx << 2)) = o1;
  }
}

// ------------------------------------------------- GEMM 2 + fused w3 dot
// ylogit[m] += sum_n relu(acc[m,n]+b2[n]) * w3[n]  (atomicAdd across N-tiles)
__global__ __launch_bounds__(256) void gemm_score_kernel(
    const float* __restrict__ A, const float* __restrict__ B,
    const float* __restrict__ bias, const float* __restrict__ w3,
    float* __restrict__ ylogit, int M, int N, int K)
{
  __shared__ float As[BK][BM + 4];
  __shared__ float Bs[BK][BN + 4];
  const int bn = blockIdx.x * BN;
  const int bm = blockIdx.y * BM;
  const int tid = threadIdx.x;
  const int tx = tid & 15, ty = (tid >> 4);
  const int lrow = tid >> 1;
  const int lk = (tid & 1) * 8;

  float acc[8][8] = {};
  const float* Aptr = A + (size_t)(bm + lrow) * K + lk;
  const float* Bptr = B + (size_t)(bn + lrow) * K + lk;

  for (int k0 = 0; k0 < K; k0 += BK) {
    float4 av0 = *(const float4*)(Aptr + k0);
    float4 av1 = *(const float4*)(Aptr + k0 + 4);
    float4 bv0 = *(const float4*)(Bptr + k0);
    float4 bv1 = *(const float4*)(Bptr + k0 + 4);
    __syncthreads();
    As[lk + 0][lrow] = av0.x; As[lk + 1][lrow] = av0.y;
    As[lk + 2][lrow] = av0.z; As[lk + 3][lrow] = av0.w;
    As[lk + 4][lrow] = av1.x; As[lk + 5][lrow] = av1.y;
    As[lk + 6][lrow] = av1.z; As[lk + 7][lrow] = av1.w;
    Bs[lk + 0][lrow] = bv0.x; Bs[lk + 1][lrow] = bv0.y;
    Bs[lk + 2][lrow] = bv0.z; Bs[lk + 3][lrow] = bv0.w;
    Bs[lk + 4][lrow] = bv1.x; Bs[lk + 5][lrow] = bv1.y;
    Bs[lk + 6][lrow] = bv1.z; Bs[lk + 7][lrow] = bv1.w;
    __syncthreads();
#pragma unroll
    for (int kk = 0; kk < BK; ++kk) {
      float4 a0 = *(const float4*)&As[kk][ty << 2];
      float4 a1 = *(const float4*)&As[kk][64 + (ty << 2)];
      float4 b0 = *(const float4*)&Bs[kk][tx << 2];
      float4 b1 = *(const float4*)&Bs[kk][64 + (tx << 2)];
      float ar[8] = {a0.x, a0.y, a0.z, a0.w, a1.x, a1.y, a1.z, a1.w};
      float br[8] = {b0.x, b0.y, b0.z, b0.w, b1.x, b1.y, b1.z, b1.w};
#pragma unroll
      for (int i = 0; i < 8; ++i)
#pragma unroll
        for (int j = 0; j < 8; ++j)
          acc[i][j] = fmaf(ar[i], br[j], acc[i][j]);
    }
  }

  const float4 bias0 = *(const float4*)&bias[bn + (tx << 2)];
  const float4 bias1 = *(const float4*)&bias[bn + 64 + (tx << 2)];
  const float4 w30 = *(const float4*)&w3[bn + (tx << 2)];
  const float4 w31 = *(const float4*)&w3[bn + 64 + (tx << 2)];
  const float bb0[4] = {bias0.x, bias0.y, bias0.z, bias0.w};
  const float bb1[4] = {bias1.x, bias1.y, bias1.z, bias1.w};
  const float ww0[4] = {w30.x, w30.y, w30.z, w30.w};
  const float ww1[4] = {w31.x, w31.y, w31.z, w31.w};

  float part[8];
#pragma unroll
  for (int i = 0; i < 8; ++i) {
    float p = 0.f;
#pragma unroll
    for (int j = 0; j < 4; ++j) {
      float v0 = acc[i][j] + bb0[j];
      float v1 = acc[i][4 + j] + bb1[j];
      v0 = v0 > 0.f ? v0 : 0.f;
      v1 = v1 > 0.f ? v1 : 0.f;
      p = fmaf(v0, ww0[j], p);
      p = fmaf(v1, ww1[j], p);
    }
    part[i] = p;
  }
  // Reduce across the 16 tx-lanes (contiguous lanes within one wave).
#pragma unroll
  for (int off = 1; off < 16; off <<= 1) {
#pragma unroll
    for (int i = 0; i < 8; ++i)
      part[i] += __shfl_xor(part[i], off, 64);
  }
  if (tx == 0) {
#pragma unroll
    for (int i = 0; i < 8; ++i) {
      const int row = bm + ((i < 4) ? (ty << 2) + i : 64 + (ty << 2) + (i - 4));
      atomicAdd(&ylogit[row], part[i]);
    }
  }
}

// ---------------------------------------------------------------- sigmoid
__global__ void sigmoid_kernel(const float* __restrict__ logit,
                               const float* __restrict__ b3,
                               float* __restrict__ ysoft, int n)
{
  int i = blockIdx.x * blockDim.x + threadIdx.x;
  if (i < n) {
    float x = logit[i] + b3[0];
    ysoft[i] = 1.f / (1.f + expf(-x));
  }
}

// ------------------------------------------------------------------ rank
// One block per batch row. rank[j] = #{y[i]<y[j]} + #{i<j: y[i]==y[j]},
// with token 0 treated as -inf (always rank 0, +1 to everyone else).
__global__ __launch_bounds__(256) void rank_kernel(
    const float* __restrict__ ysoft, float* __restrict__ yhard,
    const int* __restrict__ kptr, int S)
{
  __shared__ float row[2048];
  const int b = blockIdx.x;
  const float* y = ysoft + (size_t)b * S;
  float* out = yhard + (size_t)b * S;
  const int kk = *kptr;

  for (int i = threadIdx.x; i < S; i += 256) row[i] = y[i];
  __syncthreads();

  for (int j = threadIdx.x; j < S; j += 256) {
    if (j == 0) { out[0] = 1.0f; continue; }
    const float v = row[j];
    int cnt = 1;  // token 0 is always strictly smaller
    for (int i = 1; i < S; ++i) {
      float u = row[i];
      if (u < v || (u == v && i < j)) ++cnt;
    }
    out[j] = (cnt < kk) ? 1.0f : 0.0f;
  }
}

// ------------------------------------------------------------------ launch
extern "C" void kernel_launch(void* const* d_in, const int* in_sizes, int n_in,
                              void* d_out, int out_size, void* d_ws, size_t ws_size,
                              hipStream_t stream)
{
  const float* X  = (const float*)d_in[0];
  const float* W1 = (const float*)d_in[1];
  const float* b1 = (const float*)d_in[2];
  const float* W2 = (const float*)d_in[3];
  const float* b2 = (const float*)d_in[4];
  const float* W3 = (const float*)d_in[5];
  const float* b3 = (const float*)d_in[6];
  const int*  kpt = (const int*)d_in[7];

  const int D = 768;
  const int M = in_sizes[0] / D;   // B*S = 131072
  const int S = 2048;
  const int Bb = M / S;            // 64

  float* H1     = (float*)d_ws;            // M*D floats (~402 MB)
  float* ylogit = (float*)d_out;           // first M floats, scratch
  float* yhard  = (float*)d_out;
  float* ysoft  = ((float*)d_out) + M;

  hipMemsetAsync(ylogit, 0, (size_t)M * sizeof(float), stream);

  dim3 blk(256);
  dim3 g(D / BN, M / BM);  // (6, 1024): N-tiles fastest for A-row L2 reuse
  gemm_relu_kernel<<<g, blk, 0, stream>>>(X, W1, b1, H1, M, D, D);
  gemm_score_kernel<<<g, blk, 0, stream>>>(H1, W2, b2, W3, ylogit, M, D, D);
  sigmoid_kernel<<<dim3((M + 255) / 256), blk, 0, stream>>>(ylogit, b3, ysoft, M);
  rank_kernel<<<dim3(Bb), blk, 0, stream>>>(ysoft, yhard, kpt, S);
}

// Round 3
// 2092.463 us; speedup vs baseline: 2.3924x; 2.0827x over previous
//
#include <hip/hip_runtime.h>
#include <math.h>

// BERTStudentPruner on MI355X — fp16x2 split-precision MFMA GEMMs.
//   H1 = relu(X @ W1^T + b1)            [131072,768] -> d_ws as packed {hi,lo} uint32
//   logit = relu(H1 @ W2^T + b2) @ w3   [131072]     -> d_out[0:M] (scratch)
//   y_soft = sigmoid(logit + b3)        [131072]     -> d_out[M:2M]
//   y_hard = stable-rank(y_soft) < k    [131072]     -> d_out[0:M]
//
// Precision: no fp32 MFMA on CDNA4. Emulate: a = a_hi + 2^-11 * a_lo with
// a_hi = fp16(a), a_lo = fp16(2048*(a - a_hi)) (pre-scaled so lo stays in
// fp16 normal range; MFMA may flush subnormals). 3 MFMAs per tile:
// hi*hi -> acc1 ; hi*lo + lo*hi -> acc2 ; result = acc1 + acc2/2048.
// Dropped lo*lo term ~3e-8 abs — same error class as fp32 reorder noise,
// which already passed with absmax 0.

typedef _Float16 f16;
typedef __attribute__((ext_vector_type(8))) _Float16 half8;
typedef __attribute__((ext_vector_type(4))) float f32x4;

#define BM 128
#define BN 128
#define BK 32
#define RS 40          // LDS row stride in f16 elems (pad 32->40 to break banks)
#define INV2048 (1.0f/2048.0f)

union HU { unsigned short u; f16 f; };
static __device__ inline unsigned pack_hl(f16 h, f16 l) {
  HU a, b; a.f = h; b.f = l;
  return (unsigned)a.u | ((unsigned)b.u << 16);
}
static __device__ inline f16 u2h(unsigned short u) { HU c; c.u = u; return c.f; }

// Split 16 fp32 (in x[16]) into hi/lo half8 pairs.
#define SPLIT16(x, h0, h1, l0, l1)                                   \
  {                                                                  \
    _Pragma("unroll")                                                \
    for (int e = 0; e < 8; ++e) {                                    \
      f16 ha = (f16)x[e];      float fa = (float)ha;                 \
      f16 hb = (f16)x[8 + e];  float fb = (float)hb;                 \
      h0[e] = ha; l0[e] = (f16)((x[e] - fa) * 2048.0f);              \
      h1[e] = hb; l1[e] = (f16)((x[8 + e] - fb) * 2048.0f);          \
    }                                                                \
  }

// ---------------------------------------------------------------- GEMM 1
// A = X fp32 [M,K]; B = W1 fp32 [N,K]; out H1 packed {hi,lo} uint32 [M,N].
__global__ __launch_bounds__(256, 2) void gemm1_kernel(
    const float* __restrict__ A, const float* __restrict__ B,
    const float* __restrict__ bias, unsigned* __restrict__ H1,
    int M, int N, int K)
{
  __shared__ f16 Ah[BM * RS], Al[BM * RS], Bh[BN * RS], Bl[BN * RS];

  const int bn = blockIdx.x * BN;
  const int bm = blockIdx.y * BM;
  const int t = threadIdx.x;
  const int r = t >> 1;        // staging row 0..127
  const int h = t & 1;         // k-half (16 elems)

  const int lane = t & 63;
  const int wv = t >> 6;
  const int wm = (wv >> 1) * 64;
  const int wn = (wv & 1) * 64;
  const int i16 = lane & 15;
  const int quad = lane >> 4;

  f32x4 acc1[4][4] = {};
  f32x4 acc2[4][4] = {};

  const float* Ag = A + (size_t)(bm + r) * K + h * 16;
  const float* Bg = B + (size_t)(bn + r) * K + h * 16;

  for (int k0 = 0; k0 < K; k0 += BK) {
    float xa[16], xb[16];
    *(float4*)&xa[0]  = *(const float4*)(Ag + k0);
    *(float4*)&xa[4]  = *(const float4*)(Ag + k0 + 4);
    *(float4*)&xa[8]  = *(const float4*)(Ag + k0 + 8);
    *(float4*)&xa[12] = *(const float4*)(Ag + k0 + 12);
    *(float4*)&xb[0]  = *(const float4*)(Bg + k0);
    *(float4*)&xb[4]  = *(const float4*)(Bg + k0 + 4);
    *(float4*)&xb[8]  = *(const float4*)(Bg + k0 + 8);
    *(float4*)&xb[12] = *(const float4*)(Bg + k0 + 12);

    half8 ah0, ah1, al0, al1, bh0, bh1, bl0, bl1;
    SPLIT16(xa, ah0, ah1, al0, al1);
    SPLIT16(xb, bh0, bh1, bl0, bl1);

    __syncthreads();
    const int so = r * RS + h * 16;
    *(half8*)&Ah[so] = ah0; *(half8*)&Ah[so + 8] = ah1;
    *(half8*)&Al[so] = al0; *(half8*)&Al[so + 8] = al1;
    *(half8*)&Bh[so] = bh0; *(half8*)&Bh[so + 8] = bh1;
    *(half8*)&Bl[so] = bl0; *(half8*)&Bl[so + 8] = bl1;
    __syncthreads();

    half8 fah[4], fal[4], fbh[4], fbl[4];
#pragma unroll
    for (int i = 0; i < 4; ++i) {
      const int ao = (wm + i * 16 + i16) * RS + quad * 8;
      const int bo = (wn + i * 16 + i16) * RS + quad * 8;
      fah[i] = *(const half8*)&Ah[ao];
      fal[i] = *(const half8*)&Al[ao];
      fbh[i] = *(const half8*)&Bh[bo];
      fbl[i] = *(const half8*)&Bl[bo];
    }
#pragma unroll
    for (int im = 0; im < 4; ++im)
#pragma unroll
      for (int in = 0; in < 4; ++in) {
        acc1[im][in] = __builtin_amdgcn_mfma_f32_16x16x32_f16(
            fah[im], fbh[in], acc1[im][in], 0, 0, 0);
        acc2[im][in] = __builtin_amdgcn_mfma_f32_16x16x32_f16(
            fah[im], fbl[in], acc2[im][in], 0, 0, 0);
        acc2[im][in] = __builtin_amdgcn_mfma_f32_16x16x32_f16(
            fal[im], fbh[in], acc2[im][in], 0, 0, 0);
      }
  }

  // Epilogue: combine, +bias, relu, split to {hi,lo} packed uint32.
#pragma unroll
  for (int in = 0; in < 4; ++in) {
    const int col = bn + wn + in * 16 + i16;
    const float bv = bias[col];
#pragma unroll
    for (int im = 0; im < 4; ++im) {
#pragma unroll
      for (int reg = 0; reg < 4; ++reg) {
        const int row = bm + wm + im * 16 + quad * 4 + reg;
        float v = acc1[im][in][reg] + acc2[im][in][reg] * INV2048 + bv;
        v = v > 0.f ? v : 0.f;
        f16 hv = (f16)v;
        f16 lv = (f16)((v - (float)hv) * 2048.0f);
        H1[(size_t)row * N + col] = pack_hl(hv, lv);
      }
    }
  }
}

// ---------------------------------------------------------------- GEMM 2
// A = H1 packed {hi,lo} uint32 [M,K]; B = W2 fp32 [N,K]; fused w3 dot.
__global__ __launch_bounds__(256, 2) void gemm2_kernel(
    const unsigned* __restrict__ A, const float* __restrict__ B,
    const float* __restrict__ bias, const float* __restrict__ w3,
    float* __restrict__ ylogit, int M, int N, int K)
{
  __shared__ f16 Ah[BM * RS], Al[BM * RS], Bh[BN * RS], Bl[BN * RS];

  const int bn = blockIdx.x * BN;
  const int bm = blockIdx.y * BM;
  const int t = threadIdx.x;
  const int r = t >> 1;
  const int h = t & 1;

  const int lane = t & 63;
  const int wv = t >> 6;
  const int wm = (wv >> 1) * 64;
  const int wn = (wv & 1) * 64;
  const int i16 = lane & 15;
  const int quad = lane >> 4;

  f32x4 acc1[4][4] = {};
  f32x4 acc2[4][4] = {};

  const unsigned* Ag = A + (size_t)(bm + r) * K + h * 16;
  const float* Bg = B + (size_t)(bn + r) * K + h * 16;

  for (int k0 = 0; k0 < K; k0 += BK) {
    unsigned ua[16];
    float xb[16];
    *(uint4*)&ua[0]  = *(const uint4*)(Ag + k0);
    *(uint4*)&ua[4]  = *(const uint4*)(Ag + k0 + 4);
    *(uint4*)&ua[8]  = *(const uint4*)(Ag + k0 + 8);
    *(uint4*)&ua[12] = *(const uint4*)(Ag + k0 + 12);
    *(float4*)&xb[0]  = *(const float4*)(Bg + k0);
    *(float4*)&xb[4]  = *(const float4*)(Bg + k0 + 4);
    *(float4*)&xb[8]  = *(const float4*)(Bg + k0 + 8);
    *(float4*)&xb[12] = *(const float4*)(Bg + k0 + 12);

    half8 ah0, ah1, al0, al1, bh0, bh1, bl0, bl1;
#pragma unroll
    for (int e = 0; e < 8; ++e) {
      ah0[e] = u2h((unsigned short)(ua[e] & 0xffffu));
      al0[e] = u2h((unsigned short)(ua[e] >> 16));
      ah1[e] = u2h((unsigned short)(ua[8 + e] & 0xffffu));
      al1[e] = u2h((unsigned short)(ua[8 + e] >> 16));
    }
    SPLIT16(xb, bh0, bh1, bl0, bl1);

    __syncthreads();
    const int so = r * RS + h * 16;
    *(half8*)&Ah[so] = ah0; *(half8*)&Ah[so + 8] = ah1;
    *(half8*)&Al[so] = al0; *(half8*)&Al[so + 8] = al1;
    *(half8*)&Bh[so] = bh0; *(half8*)&Bh[so + 8] = bh1;
    *(half8*)&Bl[so] = bl0; *(half8*)&Bl[so + 8] = bl1;
    __syncthreads();

    half8 fah[4], fal[4], fbh[4], fbl[4];
#pragma unroll
    for (int i = 0; i < 4; ++i) {
      const int ao = (wm + i * 16 + i16) * RS + quad * 8;
      const int bo = (wn + i * 16 + i16) * RS + quad * 8;
      fah[i] = *(const half8*)&Ah[ao];
      fal[i] = *(const half8*)&Al[ao];
      fbh[i] = *(const half8*)&Bh[bo];
      fbl[i] = *(const half8*)&Bl[bo];
    }
#pragma unroll
    for (int im = 0; im < 4; ++im)
#pragma unroll
      for (int in = 0; in < 4; ++in) {
        acc1[im][in] = __builtin_amdgcn_mfma_f32_16x16x32_f16(
            fah[im], fbh[in], acc1[im][in], 0, 0, 0);
        acc2[im][in] = __builtin_amdgcn_mfma_f32_16x16x32_f16(
            fah[im], fbl[in], acc2[im][in], 0, 0, 0);
        acc2[im][in] = __builtin_amdgcn_mfma_f32_16x16x32_f16(
            fal[im], fbh[in], acc2[im][in], 0, 0, 0);
      }
  }

  // Epilogue: relu(acc + b2) dot w3 over this tile's 128 cols -> atomicAdd.
  float psum[4][4];  // [im][reg]
#pragma unroll
  for (int im = 0; im < 4; ++im)
#pragma unroll
    for (int reg = 0; reg < 4; ++reg) psum[im][reg] = 0.f;

#pragma unroll
  for (int in = 0; in < 4; ++in) {
    const int col = bn + wn + in * 16 + i16;
    const float bv = bias[col];
    const float wv3 = w3[col];
#pragma unroll
    for (int im = 0; im < 4; ++im)
#pragma unroll
      for (int reg = 0; reg < 4; ++reg) {
        float v = acc1[im][in][reg] + acc2[im][in][reg] * INV2048 + bv;
        v = v > 0.f ? v : 0.f;
        psum[im][reg] = fmaf(v, wv3, psum[im][reg]);
      }
  }
#pragma unroll
  for (int off = 1; off < 16; off <<= 1)
#pragma unroll
    for (int im = 0; im < 4; ++im)
#pragma unroll
      for (int reg = 0; reg < 4; ++reg)
        psum[im][reg] += __shfl_xor(psum[im][reg], off, 64);

  if (i16 == 0) {
#pragma unroll
    for (int im = 0; im < 4; ++im)
#pragma unroll
      for (int reg = 0; reg < 4; ++reg)
        atomicAdd(&ylogit[bm + wm + im * 16 + quad * 4 + reg], psum[im][reg]);
  }
}

// ---------------------------------------------------------------- sigmoid
__global__ void sigmoid_kernel(const float* __restrict__ logit,
                               const float* __restrict__ b3,
                               float* __restrict__ ysoft, int n)
{
  int i = blockIdx.x * blockDim.x + threadIdx.x;
  if (i < n) {
    float x = logit[i] + b3[0];
    ysoft[i] = 1.f / (1.f + expf(-x));
  }
}

// ------------------------------------------------------------------ rank
__global__ __launch_bounds__(256) void rank_kernel(
    const float* __restrict__ ysoft, float* __restrict__ yhard,
    const int* __restrict__ kptr, int S)
{
  __shared__ float row[2048];
  const int b = blockIdx.x;
  const float* y = ysoft + (size_t)b * S;
  float* out = yhard + (size_t)b * S;
  const int kk = *kptr;

  for (int i = threadIdx.x; i < S; i += 256) row[i] = y[i];
  __syncthreads();

  for (int j = threadIdx.x; j < S; j += 256) {
    if (j == 0) { out[0] = 1.0f; continue; }
    const float v = row[j];
    int cnt = 1;  // token 0 always strictly smaller
    for (int i = 1; i < S; ++i) {
      float u = row[i];
      if (u < v || (u == v && i < j)) ++cnt;
    }
    out[j] = (cnt < kk) ? 1.0f : 0.0f;
  }
}

// ------------------------------------------------------------------ launch
extern "C" void kernel_launch(void* const* d_in, const int* in_sizes, int n_in,
                              void* d_out, int out_size, void* d_ws, size_t ws_size,
                              hipStream_t stream)
{
  const float* X  = (const float*)d_in[0];
  const float* W1 = (const float*)d_in[1];
  const float* b1 = (const float*)d_in[2];
  const float* W2 = (const float*)d_in[3];
  const float* b2 = (const float*)d_in[4];
  const float* W3 = (const float*)d_in[5];
  const float* b3 = (const float*)d_in[6];
  const int*  kpt = (const int*)d_in[7];

  const int D = 768;
  const int M = in_sizes[0] / D;   // 131072
  const int S = 2048;
  const int Bb = M / S;            // 64

  unsigned* H1  = (unsigned*)d_ws;         // M*D packed {hi,lo} (~403 MB)
  float* ylogit = (float*)d_out;           // first M floats (scratch)
  float* yhard  = (float*)d_out;
  float* ysoft  = ((float*)d_out) + M;

  hipMemsetAsync(ylogit, 0, (size_t)M * sizeof(float), stream);

  dim3 blk(256);
  dim3 g(D / BN, M / BM);  // (6, 1024)
  gemm1_kernel<<<g, blk, 0, stream>>>(X, W1, b1, H1, M, D, D);
  gemm2_kernel<<<g, blk, 0, stream>>>(H1, W2, b2, W3, ylogit, M, D, D);
  sigmoid_kernel<<<dim3((M + 255) / 256), blk, 0, stream>>>(ylogit, b3, ysoft, M);
  rank_kernel<<<dim3(Bb), blk, 0, stream>>>(ysoft, yhard, kpt, S);
}